// Round 15
// baseline (75.001 us; speedup 1.0000x reference)
//
#include <hip/hip_runtime.h>
#include <math.h>

typedef __bf16 bf16;
typedef __attribute__((ext_vector_type(4))) __bf16 bf16x4;
typedef __attribute__((ext_vector_type(8))) __bf16 bf16x8;
typedef __attribute__((ext_vector_type(4))) float f32x4;

#define MFMA16(a, b, c) __builtin_amdgcn_mfma_f32_16x16x32_bf16(a, b, c, 0, 0, 0)

struct P {
    const float* x; const float* sw; const float* sb; const float* w0;
    float* out;
    bf16 *WB, *XF, *XO, *A1F, *S1F, *A2TF, *S2TF, *A2GF, *S2GF, *SPD;
    float *sag, *ssg;
};

// ---------------------------------------------------------------------------
// k_init: vb<256 -> XF; vb<512 -> XO; vb<596 -> WB; vb<612 -> gates (fp32)
// ---------------------------------------------------------------------------
__global__ __launch_bounds__(256) void k_init(P p) {
    const int vb = blockIdx.x, vt = threadIdx.x;
    const int l = vt & 63, kb = vt >> 6;
    if (vb < 512) {
        const int col0 = (l >> 4) * 8;
#pragma unroll
        for (int pass = 0; pass < 2; ++pass) {
            const int kg = kb + pass * 4;
            size_t row;
            bf16* dst;
            if (vb < 256) {
                row = (size_t)(vb * 16 + (l & 15));
                dst = p.XF + ((size_t)(vb * 8 + kg) * 64 + l) * 8;
            } else {
                const int c = (vb - 256) >> 3, bb = (vb - 256) & 7;
                row = (size_t)((c * 16 + (l & 15)) * 8 + bb);
                dst = p.XO + ((size_t)(((c * 8 + bb) * 8) + kg) * 64 + l) * 8;
            }
            const float4 v0 = *(const float4*)(p.x + row * 256 + kg * 32 + col0);
            const float4 v1 = *(const float4*)(p.x + row * 256 + kg * 32 + col0 + 4);
            bf16x8 o;
            o[0] = (bf16)v0.x; o[1] = (bf16)v0.y; o[2] = (bf16)v0.z; o[3] = (bf16)v0.w;
            o[4] = (bf16)v1.x; o[5] = (bf16)v1.y; o[6] = (bf16)v1.z; o[7] = (bf16)v1.w;
            *(bf16x8*)dst = o;
        }
        return;
    }
    if (vb < 596) {
        const int nb = vb - 512;                  // 0..83
        const int n = nb * 16 + (l & 15);
#pragma unroll
        for (int pass = 0; pass < 2; ++pass) {
            const int kk = kb + pass * 4;
            const int i0 = kk * 32 + (l >> 4) * 8;
            bf16x8 o;
            if (n < 1282) {
                const float* src = (n < 1024) ? (p.sw + (size_t)n * 256)
                                 : (n < 1280) ? (p.w0 + (size_t)(n - 1024) * 256)
                                              : (p.sw + (size_t)(1024 + (n - 1280)) * 256);
#pragma unroll
                for (int e = 0; e < 8; ++e) o[e] = (bf16)src[i0 + e];
            } else {
#pragma unroll
                for (int e = 0; e < 8; ++e) o[e] = (bf16)0.0f;
            }
            *(bf16x8*)(p.WB + ((size_t)(nb * 8 + kk) * 64 + l) * 8) = o;
        }
        return;
    }
    // ---- gates: one row per thread, fp32 dots + sigmoid ----
    {
        const int row = (vb - 596) * 256 + vt;    // 0..4095
        const float4* xr = (const float4*)(p.x + (size_t)row * 256);
        const float4* wa = (const float4*)(p.sw + (size_t)1024 * 256);
        const float4* ws = (const float4*)(p.sw + (size_t)1025 * 256);
        float a0 = 0.f, a1 = 0.f, s0 = 0.f, s1 = 0.f;
        for (int i4 = 0; i4 < 64; i4 += 2) {
            const float4 xv0 = xr[i4], xv1 = xr[i4 + 1];
            const float4 wa0 = wa[i4], wa1 = wa[i4 + 1];
            const float4 ws0 = ws[i4], ws1 = ws[i4 + 1];
            a0 = fmaf(xv0.x, wa0.x, a0); a0 = fmaf(xv0.y, wa0.y, a0);
            a0 = fmaf(xv0.z, wa0.z, a0); a0 = fmaf(xv0.w, wa0.w, a0);
            a1 = fmaf(xv1.x, wa1.x, a1); a1 = fmaf(xv1.y, wa1.y, a1);
            a1 = fmaf(xv1.z, wa1.z, a1); a1 = fmaf(xv1.w, wa1.w, a1);
            s0 = fmaf(xv0.x, ws0.x, s0); s0 = fmaf(xv0.y, ws0.y, s0);
            s0 = fmaf(xv0.z, ws0.z, s0); s0 = fmaf(xv0.w, ws0.w, s0);
            s1 = fmaf(xv1.x, ws1.x, s1); s1 = fmaf(xv1.y, ws1.y, s1);
            s1 = fmaf(xv1.z, ws1.z, s1); s1 = fmaf(xv1.w, ws1.w, s1);
        }
        const float za = a0 + a1 + p.sb[1024];
        const float zs = s0 + s1 + p.sb[1025];
        p.sag[row] = 1.0f / (1.0f + expf(-za));
        p.ssg[row] = 1.0f / (1.0f + expf(-zs));
    }
}

// ---------------------------------------------------------------------------
// k_prep (r13 layouts): grid (64, 16).
//  nb 0..3 -> A1F; 4..7 -> A2TF + A2GF; 8..11 -> S1F; 12..15 -> S2TF + S2GF
// ---------------------------------------------------------------------------
__global__ __launch_bounds__(256) void k_prep(P p) {
    const int mb = blockIdx.x, nb = blockIdx.y;
    const int vt = threadIdx.x;
    const int l = vt & 63, w = vt >> 6;
    const int lr = l & 15, lc = l >> 4;
    const int n0 = nb * 64;

    f32x4 acc[4];
#pragma unroll
    for (int ni = 0; ni < 4; ++ni) acc[ni] = (f32x4){0.f, 0.f, 0.f, 0.f};

#pragma unroll
    for (int kk = 0; kk < 8; ++kk) {
        const bf16x8 a = *(const bf16x8*)(p.XF + ((size_t)((mb * 4 + w) * 8 + kk) * 64 + l) * 8);
#pragma unroll
        for (int ni = 0; ni < 4; ++ni) {
            const bf16x8 b = *(const bf16x8*)(p.WB +
                ((size_t)((nb * 4 + ni) * 8 + kk) * 64 + l) * 8);
            acc[ni] = MFMA16(a, b, acc[ni]);
        }
    }

    const int typ = nb >> 2;
    const int c   = mb >> 1;                  // half-chunk 0..31
    const int kkd = ((mb & 1) << 1) | (w >> 1);
    const int lcD = ((w & 1) << 1) | (lc >> 1);
    const int laneD = lr + 16 * lcD;
    const int eoff  = (lc & 1) * 4;

    if (typ == 0 || typ == 2) {   // A1F / S1F
        bf16* dst = (typ == 0 ? p.A1F : p.S1F);
        const int tb = (typ == 0 ? nb : nb - 8) * 4;
#pragma unroll
        for (int ni = 0; ni < 4; ++ni) {
            const float bz = p.sb[n0 + ni * 16 + lr];
            bf16x4 q;
#pragma unroll
            for (int v2 = 0; v2 < 4; ++v2) q[v2] = (bf16)(acc[ni][v2] + bz);
            *(bf16x4*)(dst + ((size_t)((c * 4 + kkd) * 16 + tb + ni) * 64 + laneD) * 8 + eoff) = q;
        }
    } else {                      // A2TF/S2TF + A2GF/S2GF
        bf16* dstT = (typ == 1 ? p.A2TF : p.S2TF);
        bf16* dstG = (typ == 1 ? p.A2GF : p.S2GF);
        const int nbr = (typ == 1 ? nb - 4 : nb - 12);
        const int keytile = mb * 4 + w;
#pragma unroll
        for (int ni = 0; ni < 4; ++ni) {
            const float bz = p.sb[n0 + ni * 16 + lr];
            bf16x4 q;
#pragma unroll
            for (int v2 = 0; v2 < 4; ++v2) q[v2] = (bf16)(acc[ni][v2] + bz);
            *(bf16x4*)(dstT + ((size_t)((c * 4 + kkd) * 16 + nbr * 4 + ni) * 64 + laneD) * 8 + eoff) = q;
            const int kkg = nbr * 2 + (ni >> 1);
            const int lcG = ((ni & 1) << 1) | (lr >> 3);
            const int eG  = lr & 7;
#pragma unroll
            for (int v2 = 0; v2 < 4; ++v2)
                dstG[((size_t)(keytile * 8 + kkg) * 64 + (lc * 4 + v2) + 16 * lcG) * 8 + eG] = q[v2];
        }
    }
}

// ---------------------------------------------------------------------------
// k_delta (NCH=16, in-kernel gating on 2-tile B side): per (c,bb,ih,oh):
// delta[128 o][128 i], K=512. Gate g[t, bb] applied to B fragments (correct
// bb-indexed form, r13-verified). 512 blocks XCD-swizzled, 2 blocks/CU.
// ---------------------------------------------------------------------------
#define KD_LDA(K) {                                                          \
    const bf16* As_ = ((K) < 8) ? p.A2TF : p.S2TF;                           \
    const int h_ = 2 * c + (((K) >> 2) & 1);                                 \
    _Pragma("unroll")                                                        \
    for (int mi = 0; mi < 4; ++mi)                                           \
        aC[mi] = *(const bf16x8*)(As_ +                                      \
            ((size_t)((h_ * 4 + ((K) & 3)) * 16 + itile0 + mi) * 64 + l) * 8); }

#define KD_LDB(K, bv) {                                                      \
    const bf16* Bs_ = ((K) < 8) ? p.A1F : p.S1F;                             \
    const int h_ = 2 * c + (((K) >> 2) & 1);                                 \
    _Pragma("unroll")                                                        \
    for (int ni = 0; ni < 2; ++ni)                                           \
        bv[ni] = *(const bf16x8*)(Bs_ +                                      \
            ((size_t)((h_ * 4 + ((K) & 3)) * 16 + otile0 + ni) * 64 + l) * 8); }

#define KD_SC(K, bv) {                                                       \
    const float* gp_ = ((K) < 8) ? p.sag : p.ssg;                            \
    float g_ = gp_[(c * 32 + ((K) & 7) * 4 + lc) * 8 + bb];                  \
    if ((K) >= 8) g_ = -g_;                                                  \
    _Pragma("unroll")                                                        \
    for (int ni = 0; ni < 2; ++ni)                                           \
        _Pragma("unroll")                                                    \
        for (int e = 0; e < 8; ++e)                                          \
            bv[ni][e] = (bf16)(g_ * (float)bv[ni][e]); }

#define KD_MM(bv) {                                                          \
    _Pragma("unroll")                                                        \
    for (int ni = 0; ni < 2; ++ni)                                           \
        _Pragma("unroll")                                                    \
        for (int mi = 0; mi < 4; ++mi)                                       \
            acc[mi][ni] = MFMA16(aC[mi], bv[ni], acc[mi][ni]); }

__global__ __launch_bounds__(512, 4) void k_delta(P p) {
    const int bid = blockIdx.x;                  // 512
    const int xcd = bid & 7, idx = bid >> 3;     // idx 0..63
    const int c   = xcd + 8 * (idx >> 5);        // chunk 0..15 (XCD-local)
    const int rem = idx & 31;
    const int bb  = rem >> 2, ih = (rem >> 1) & 1, oh = rem & 1;
    const int t = threadIdx.x, l = t & 63, w = t >> 6;
    const int lc = l >> 4;
    const int itile0 = ih * 8 + (w >> 2) * 4;
    const int otile0 = oh * 8 + (w & 3) * 2;

    f32x4 acc[4][2];
#pragma unroll
    for (int mi = 0; mi < 4; ++mi)
#pragma unroll
        for (int ni = 0; ni < 2; ++ni) acc[mi][ni] = (f32x4){0.f, 0.f, 0.f, 0.f};

    bf16x8 aC[4], bX[2], bY[2];

    KD_LDB(0, bX); KD_SC(0, bX);
    KD_LDA(0);  KD_LDB(1, bY);  KD_MM(bX); KD_SC(1, bY);
    KD_LDA(1);  KD_LDB(2, bX);  KD_MM(bY); KD_SC(2, bX);
    KD_LDA(2);  KD_LDB(3, bY);  KD_MM(bX); KD_SC(3, bY);
    KD_LDA(3);  KD_LDB(4, bX);  KD_MM(bY); KD_SC(4, bX);
    KD_LDA(4);  KD_LDB(5, bY);  KD_MM(bX); KD_SC(5, bY);
    KD_LDA(5);  KD_LDB(6, bX);  KD_MM(bY); KD_SC(6, bX);
    KD_LDA(6);  KD_LDB(7, bY);  KD_MM(bX); KD_SC(7, bY);
    KD_LDA(7);  KD_LDB(8, bX);  KD_MM(bY); KD_SC(8, bX);
    KD_LDA(8);  KD_LDB(9, bY);  KD_MM(bX); KD_SC(9, bY);
    KD_LDA(9);  KD_LDB(10, bX); KD_MM(bY); KD_SC(10, bX);
    KD_LDA(10); KD_LDB(11, bY); KD_MM(bX); KD_SC(11, bY);
    KD_LDA(11); KD_LDB(12, bX); KD_MM(bY); KD_SC(12, bX);
    KD_LDA(12); KD_LDB(13, bY); KD_MM(bX); KD_SC(13, bY);
    KD_LDA(13); KD_LDB(14, bX); KD_MM(bY); KD_SC(14, bX);
    KD_LDA(14); KD_LDB(15, bY); KD_MM(bX); KD_SC(15, bY);
    KD_LDA(15); KD_MM(bY);

    const size_t base = (size_t)(c * 8 + bb) * 8;
#pragma unroll
    for (int mi = 0; mi < 4; ++mi) {
        const int kkD  = ih * 4 + (w >> 2) * 2 + (mi >> 1);
        const int slot = (l & 15) + 16 * (((mi & 1) << 1) | (lc >> 1));
        const int eoff = (lc & 1) * 4;
#pragma unroll
        for (int ni = 0; ni < 2; ++ni) {
            bf16x4 q;
#pragma unroll
            for (int v = 0; v < 4; ++v) q[v] = (bf16)(acc[mi][ni][v]);
            *(bf16x4*)(p.SPD + ((base + kkD) * 16 + otile0 + ni) * 512 + slot * 8 + eoff) = q;
        }
    }
}

// ---------------------------------------------------------------------------
// k_prefix (r13 verbatim): in-place exclusive prefix, 512 blocks.
// ---------------------------------------------------------------------------
__global__ __launch_bounds__(256) void k_prefix(P p) {
    const int idx = blockIdx.x * 256 + threadIdx.x;   // 0..131071
    bf16* q = p.SPD + (size_t)idx * 4;
    float run[4] = {0.f, 0.f, 0.f, 0.f};
    for (int g = 0; g < 2; ++g) {
        bf16x4 d[8];
#pragma unroll
        for (int cc = 0; cc < 8; ++cc)
            d[cc] = *(const bf16x4*)(q + (size_t)(g * 8 + cc) * 524288);
#pragma unroll
        for (int cc = 0; cc < 8; ++cc) {
            bf16x4 s;
#pragma unroll
            for (int e = 0; e < 4; ++e) s[e] = (bf16)run[e];
            *(bf16x4*)(q + (size_t)(g * 8 + cc) * 524288) = s;
#pragma unroll
            for (int e = 0; e < 4; ++e) run[e] += (float)d[cc][e];
        }
    }
}

// ---------------------------------------------------------------------------
// k_out (r13 verbatim): block (c,bb,jh,oh), XCD-swizzled.
// ---------------------------------------------------------------------------
__global__ __launch_bounds__(512, 4) void k_out(P p) {
    const int bid = blockIdx.x;                  // 512
    const int xcd = bid & 7, idx = bid >> 3;     // idx 0..63
    const int c   = xcd + 8 * (idx >> 5);        // chunk 0..15
    const int rem = idx & 31;
    const int bb = rem >> 2, jh = (rem >> 1) & 1, oh = rem & 1;
    const int t = threadIdx.x, l = t & 63, w = t >> 6;
    const int lr = l & 15, lc = l >> 4;
    const int ot = oh * 8 + w;                   // o-tile 0..15
    const int hq = c * 2 + jh;                   // j half-chunk

    __shared__ __align__(16) bf16 PB[16][520];

    bf16x8 xa[8];
#pragma unroll
    for (int kk = 0; kk < 8; ++kk)
        xa[kk] = *(const bf16x8*)(p.XO + ((size_t)((hq * 8 + bb) * 8 + kk) * 64 + l) * 8);

    // ---- S^T phase over key halves hh = 0..jh ----
#pragma unroll
    for (int hh = 0; hh < 2; ++hh) {
        if (hh > jh) break;
        const int hk = c * 2 + hh;
        f32x4 sA = (f32x4){0.f, 0.f, 0.f, 0.f};
        f32x4 sS = (f32x4){0.f, 0.f, 0.f, 0.f};
#pragma unroll
        for (int kk = 0; kk < 8; ++kk) {
            const size_t ko = ((size_t)((hk * 8 + w) * 8 + kk) * 64 + l) * 8;
            sA = MFMA16(*(const bf16x8*)(p.A2GF + ko), xa[kk], sA);
            sS = MFMA16(*(const bf16x8*)(p.S2GF + ko), xa[kk], sS);
        }
        const int tl = w * 2 + (lc >> 1);
        const float ga =  p.sag[(c * 32 + hh * 16 + tl) * 8 + bb];
        const float gs = -p.ssg[(c * 32 + hh * 16 + tl) * 8 + bb];
        const bool m = (hh == jh) && (tl > lr);
        bf16x4 pa, ps;
#pragma unroll
        for (int v = 0; v < 4; ++v) {
            pa[v] = (bf16)(m ? 0.f : ga * sA[v]);
            ps[v] = (bf16)(m ? 0.f : gs * sS[v]);
        }
        *(bf16x4*)&PB[lr][hh * 128 + w * 16 + lc * 4]       = pa;
        *(bf16x4*)&PB[lr][256 + hh * 128 + w * 16 + lc * 4] = ps;
    }

    // ---- inter (state c) + base (W0) while PB settles ----
    f32x4 acco = (f32x4){0.f, 0.f, 0.f, 0.f};
#pragma unroll
    for (int kk = 0; kk < 8; ++kk) {
        const bf16x8 b = *(const bf16x8*)(p.SPD +
            ((size_t)(((c * 8 + bb) * 8 + kk) * 16 + ot) * 64 + l) * 8);
        acco = MFMA16(xa[kk], b, acco);
    }
#pragma unroll
    for (int kk = 0; kk < 8; ++kk) {
        const bf16x8 b = *(const bf16x8*)(p.WB +
            (((size_t)(64 + ot) * 8 + kk) * 64 + l) * 8);
        acco = MFMA16(xa[kk], b, acco);
    }

    __syncthreads();   // PB visible

    // ---- intra out phase over key halves ----
#pragma unroll
    for (int hh = 0; hh < 2; ++hh) {
        if (hh > jh) break;
        const int hk = c * 2 + hh;
#pragma unroll
        for (int kk2 = 0; kk2 < 4; ++kk2) {
            const bf16x8 af = *(const bf16x8*)&PB[lr][hh * 128 + kk2 * 32 + lc * 8];
            const bf16x8 b = *(const bf16x8*)(p.A1F +
                ((size_t)((hk * 4 + kk2) * 16 + ot) * 64 + l) * 8);
            acco = MFMA16(af, b, acco);
        }
#pragma unroll
        for (int kk2 = 0; kk2 < 4; ++kk2) {
            const bf16x8 af = *(const bf16x8*)&PB[lr][256 + hh * 128 + kk2 * 32 + lc * 8];
            const bf16x8 b = *(const bf16x8*)(p.S1F +
                ((size_t)((hk * 4 + kk2) * 16 + ot) * 64 + l) * 8);
            acco = MFMA16(af, b, acco);
        }
    }

    // ---- pure write ----
#pragma unroll
    for (int v = 0; v < 4; ++v) {
        const size_t jb = (size_t)((hq * 16 + lc * 4 + v) * 8 + bb);
        p.out[jb * 256 + ot * 16 + lr] = acco[v];
    }
}

// ---------------------------------------------------------------------------
extern "C" void kernel_launch(void* const* d_in, const int* in_sizes, int n_in,
                              void* d_out, int out_size, void* d_ws, size_t ws_size,
                              hipStream_t stream) {
    char* ws = (char*)d_ws;
    P hp;
    hp.x  = (const float*)d_in[0];
    hp.sw = (const float*)d_in[1];
    hp.sb = (const float*)d_in[2];
    hp.w0 = (const float*)d_in[3];
    hp.out = (float*)d_out;
    hp.WB   = (bf16*)(ws + 0);
    hp.XF   = (bf16*)(ws + 688128);
    hp.XO   = (bf16*)(ws + 2785280);
    hp.A1F  = (bf16*)(ws + 4882432);
    hp.S1F  = (bf16*)(ws + 6979584);
    hp.A2TF = (bf16*)(ws + 9076736);
    hp.S2TF = (bf16*)(ws + 11173888);
    hp.A2GF = (bf16*)(ws + 13271040);
    hp.S2GF = (bf16*)(ws + 15368192);
    hp.sag  = (float*)(ws + 17465344);     // 16 KB
    hp.ssg  = (float*)(ws + 17481728);     // 16 KB
    hp.SPD  = (bf16*)(ws + 17498112);      // 16 MB

    k_init<<<612, 256, 0, stream>>>(hp);
    dim3 gp(64, 16);
    k_prep<<<gp, 256, 0, stream>>>(hp);
    k_delta<<<512, 512, 0, stream>>>(hp);
    k_prefix<<<512, 256, 0, stream>>>(hp);
    k_out<<<512, 512, 0, stream>>>(hp);
}

// Round 16
// 57.159 us; speedup vs baseline: 1.3122x; 1.3122x over previous
//
#include <hip/hip_runtime.h>
#include <math.h>

typedef __bf16 bf16;
typedef __attribute__((ext_vector_type(4))) __bf16 bf16x4;
typedef __attribute__((ext_vector_type(8))) __bf16 bf16x8;
typedef __attribute__((ext_vector_type(4))) float f32x4;

#define MFMA16(a, b, c) __builtin_amdgcn_mfma_f32_16x16x32_bf16(a, b, c, 0, 0, 0)

struct P {
    const float* x; const float* sw; const float* sb; const float* w0;
    float* out;
    bf16 *WB, *XF, *XO, *A1F, *S1F, *A2TF, *S2TF, *A2GF, *S2GF, *SPD;
    float *sag, *ssg;
};

// ---------------------------------------------------------------------------
// k_init (r13 verbatim): bid<256 -> XF; bid<512 -> XO; else WB (84 tiles)
// ---------------------------------------------------------------------------
__global__ __launch_bounds__(256) void k_init(P p) {
    const int vb = blockIdx.x, vt = threadIdx.x;
    const int l = vt & 63, kb = vt >> 6;
    if (vb < 512) {
        const int col0 = (l >> 4) * 8;
#pragma unroll
        for (int pass = 0; pass < 2; ++pass) {
            const int kg = kb + pass * 4;
            size_t row;
            bf16* dst;
            if (vb < 256) {
                row = (size_t)(vb * 16 + (l & 15));
                dst = p.XF + ((size_t)(vb * 8 + kg) * 64 + l) * 8;
            } else {
                const int c = (vb - 256) >> 3, bb = (vb - 256) & 7;
                row = (size_t)((c * 16 + (l & 15)) * 8 + bb);
                dst = p.XO + ((size_t)(((c * 8 + bb) * 8) + kg) * 64 + l) * 8;
            }
            const float4 v0 = *(const float4*)(p.x + row * 256 + kg * 32 + col0);
            const float4 v1 = *(const float4*)(p.x + row * 256 + kg * 32 + col0 + 4);
            bf16x8 o;
            o[0] = (bf16)v0.x; o[1] = (bf16)v0.y; o[2] = (bf16)v0.z; o[3] = (bf16)v0.w;
            o[4] = (bf16)v1.x; o[5] = (bf16)v1.y; o[6] = (bf16)v1.z; o[7] = (bf16)v1.w;
            *(bf16x8*)dst = o;
        }
        return;
    }
    const int nb = vb - 512;                  // 0..83
    const int n = nb * 16 + (l & 15);
#pragma unroll
    for (int pass = 0; pass < 2; ++pass) {
        const int kk = kb + pass * 4;
        const int i0 = kk * 32 + (l >> 4) * 8;
        bf16x8 o;
        if (n < 1282) {
            const float* src = (n < 1024) ? (p.sw + (size_t)n * 256)
                             : (n < 1280) ? (p.w0 + (size_t)(n - 1024) * 256)
                                          : (p.sw + (size_t)(1024 + (n - 1280)) * 256);
#pragma unroll
            for (int e = 0; e < 8; ++e) o[e] = (bf16)src[i0 + e];
        } else {
#pragma unroll
            for (int e = 0; e < 8; ++e) o[e] = (bf16)0.0f;
        }
        *(bf16x8*)(p.WB + ((size_t)(nb * 8 + kk) * 64 + l) * 8) = o;
    }
}

// ---------------------------------------------------------------------------
// k_prep (r13 verbatim): grid (64, 17); y==16 -> gates (nb=20).
// ---------------------------------------------------------------------------
__global__ __launch_bounds__(256) void k_prep(P p) {
    const int mb = blockIdx.x;
    const int nb = (blockIdx.y == 16) ? 20 : blockIdx.y;
    const int vt = threadIdx.x;
    const int l = vt & 63, w = vt >> 6;
    const int lr = l & 15, lc = l >> 4;
    const int rw = mb * 64 + w * 16;
    const int n0 = nb * 64;

    f32x4 acc[4];
#pragma unroll
    for (int ni = 0; ni < 4; ++ni) acc[ni] = (f32x4){0.f, 0.f, 0.f, 0.f};

#pragma unroll
    for (int kk = 0; kk < 8; ++kk) {
        const bf16x8 a = *(const bf16x8*)(p.XF + ((size_t)((mb * 4 + w) * 8 + kk) * 64 + l) * 8);
#pragma unroll
        for (int ni = 0; ni < 4; ++ni) {
            const bf16x8 b = *(const bf16x8*)(p.WB +
                ((size_t)((nb * 4 + ni) * 8 + kk) * 64 + l) * 8);
            acc[ni] = MFMA16(a, b, acc[ni]);
        }
    }

    if (nb == 20) {   // gates
        if (lr < 2) {
            const float bz = p.sb[1024 + lr];
            float* dst = lr ? p.ssg : p.sag;
#pragma unroll
            for (int v2 = 0; v2 < 4; ++v2) {
                const float z = acc[0][v2] + bz;
                dst[rw + lc * 4 + v2] = 1.0f / (1.0f + expf(-z));
            }
        }
        return;
    }

    const int typ = nb >> 2;
    const int c   = mb >> 1;                  // half-chunk 0..31
    const int kkd = ((mb & 1) << 1) | (w >> 1);
    const int lcD = ((w & 1) << 1) | (lc >> 1);
    const int laneD = lr + 16 * lcD;
    const int eoff  = (lc & 1) * 4;

    if (typ == 0 || typ == 2) {   // A1F / S1F
        bf16* dst = (typ == 0 ? p.A1F : p.S1F);
        const int tb = (typ == 0 ? nb : nb - 8) * 4;
#pragma unroll
        for (int ni = 0; ni < 4; ++ni) {
            const float bz = p.sb[n0 + ni * 16 + lr];
            bf16x4 q;
#pragma unroll
            for (int v2 = 0; v2 < 4; ++v2) q[v2] = (bf16)(acc[ni][v2] + bz);
            *(bf16x4*)(dst + ((size_t)((c * 4 + kkd) * 16 + tb + ni) * 64 + laneD) * 8 + eoff) = q;
        }
    } else {                      // A2TF/S2TF + A2GF/S2GF
        bf16* dstT = (typ == 1 ? p.A2TF : p.S2TF);
        bf16* dstG = (typ == 1 ? p.A2GF : p.S2GF);
        const int nbr = (typ == 1 ? nb - 4 : nb - 12);
        const int keytile = mb * 4 + w;
#pragma unroll
        for (int ni = 0; ni < 4; ++ni) {
            const float bz = p.sb[n0 + ni * 16 + lr];
            bf16x4 q;
#pragma unroll
            for (int v2 = 0; v2 < 4; ++v2) q[v2] = (bf16)(acc[ni][v2] + bz);
            *(bf16x4*)(dstT + ((size_t)((c * 4 + kkd) * 16 + nbr * 4 + ni) * 64 + laneD) * 8 + eoff) = q;
            const int kkg = nbr * 2 + (ni >> 1);
            const int lcG = ((ni & 1) << 1) | (lr >> 3);
            const int eG  = lr & 7;
#pragma unroll
            for (int v2 = 0; v2 < 4; ++v2)
                dstG[((size_t)(keytile * 8 + kkg) * 64 + (lc * 4 + v2) + 16 * lcG) * 8 + eG] = q[v2];
        }
    }
}

// ---------------------------------------------------------------------------
// k_delta (r13 verbatim): per (c,bb,ih): delta[256 o][128 i-half], K=512.
// 256 blocks XCD-swizzled; in-kernel gating (bb-indexed, verified).
// ---------------------------------------------------------------------------
#define KD_LDA(K) {                                                          \
    const bf16* As_ = ((K) < 8) ? p.A2TF : p.S2TF;                           \
    const int h_ = 2 * c + (((K) >> 2) & 1);                                 \
    _Pragma("unroll")                                                        \
    for (int mi = 0; mi < 4; ++mi)                                           \
        aC[mi] = *(const bf16x8*)(As_ +                                      \
            ((size_t)((h_ * 4 + ((K) & 3)) * 16 + itile0 + mi) * 64 + l) * 8); }

#define KD_LDB(K, bv) {                                                      \
    const bf16* Bs_ = ((K) < 8) ? p.A1F : p.S1F;                             \
    const int h_ = 2 * c + (((K) >> 2) & 1);                                 \
    _Pragma("unroll")                                                        \
    for (int ni = 0; ni < 4; ++ni)                                           \
        bv[ni] = *(const bf16x8*)(Bs_ +                                      \
            ((size_t)((h_ * 4 + ((K) & 3)) * 16 + otile0 + ni) * 64 + l) * 8); }

#define KD_SC(K, bv) {                                                       \
    const float* gp_ = ((K) < 8) ? p.sag : p.ssg;                            \
    float g_ = gp_[(c * 32 + ((K) & 7) * 4 + lc) * 8 + bb];                  \
    if ((K) >= 8) g_ = -g_;                                                  \
    _Pragma("unroll")                                                        \
    for (int ni = 0; ni < 4; ++ni)                                           \
        _Pragma("unroll")                                                    \
        for (int e = 0; e < 8; ++e)                                          \
            bv[ni][e] = (bf16)(g_ * (float)bv[ni][e]); }

#define KD_MM(bv) {                                                          \
    _Pragma("unroll")                                                        \
    for (int ni = 0; ni < 4; ++ni)                                           \
        _Pragma("unroll")                                                    \
        for (int mi = 0; mi < 4; ++mi)                                       \
            acc[mi][ni] = MFMA16(aC[mi], bv[ni], acc[mi][ni]); }

__global__ __launch_bounds__(512, 2) void k_delta(P p) {
    const int bid = blockIdx.x;                  // 256
    const int xcd = bid & 7, idx = bid >> 3;     // idx 0..31
    const int c   = xcd + 8 * (idx >> 4);        // chunk 0..15 (XCD-local)
    const int rem = idx & 15;
    const int bb  = rem >> 1, ih = rem & 1;
    const int t = threadIdx.x, l = t & 63, w = t >> 6;
    const int lc = l >> 4;
    const int itile0 = ih * 8 + (w >> 2) * 4;
    const int otile0 = (w & 3) * 4;

    f32x4 acc[4][4];
#pragma unroll
    for (int mi = 0; mi < 4; ++mi)
#pragma unroll
        for (int ni = 0; ni < 4; ++ni) acc[mi][ni] = (f32x4){0.f, 0.f, 0.f, 0.f};

    bf16x8 aC[4], bX[4], bY[4];

    KD_LDB(0, bX); KD_SC(0, bX);
    KD_LDA(0);  KD_LDB(1, bY);  KD_MM(bX); KD_SC(1, bY);
    KD_LDA(1);  KD_LDB(2, bX);  KD_MM(bY); KD_SC(2, bX);
    KD_LDA(2);  KD_LDB(3, bY);  KD_MM(bX); KD_SC(3, bY);
    KD_LDA(3);  KD_LDB(4, bX);  KD_MM(bY); KD_SC(4, bX);
    KD_LDA(4);  KD_LDB(5, bY);  KD_MM(bX); KD_SC(5, bY);
    KD_LDA(5);  KD_LDB(6, bX);  KD_MM(bY); KD_SC(6, bX);
    KD_LDA(6);  KD_LDB(7, bY);  KD_MM(bX); KD_SC(7, bY);
    KD_LDA(7);  KD_LDB(8, bX);  KD_MM(bY); KD_SC(8, bX);
    KD_LDA(8);  KD_LDB(9, bY);  KD_MM(bX); KD_SC(9, bY);
    KD_LDA(9);  KD_LDB(10, bX); KD_MM(bY); KD_SC(10, bX);
    KD_LDA(10); KD_LDB(11, bY); KD_MM(bX); KD_SC(11, bY);
    KD_LDA(11); KD_LDB(12, bX); KD_MM(bY); KD_SC(12, bX);
    KD_LDA(12); KD_LDB(13, bY); KD_MM(bX); KD_SC(13, bY);
    KD_LDA(13); KD_LDB(14, bX); KD_MM(bY); KD_SC(14, bX);
    KD_LDA(14); KD_LDB(15, bY); KD_MM(bX); KD_SC(15, bY);
    KD_LDA(15); KD_MM(bY);

    const size_t base = (size_t)(c * 8 + bb) * 8;
#pragma unroll
    for (int mi = 0; mi < 4; ++mi) {
        const int kkD  = ih * 4 + (w >> 2) * 2 + (mi >> 1);
        const int slot = (l & 15) + 16 * (((mi & 1) << 1) | (lc >> 1));
        const int eoff = (lc & 1) * 4;
#pragma unroll
        for (int ni = 0; ni < 4; ++ni) {
            bf16x4 q;
#pragma unroll
            for (int v = 0; v < 4; ++v) q[v] = (bf16)(acc[mi][ni][v]);
            *(bf16x4*)(p.SPD + ((base + kkD) * 16 + otile0 + ni) * 512 + slot * 8 + eoff) = q;
        }
    }
}

// ---------------------------------------------------------------------------
// k_prefix (r13 + full 16-deep load batch): in-place exclusive prefix.
// All 16 chunk-loads issued before the store+accumulate sweep (max MLP).
// ---------------------------------------------------------------------------
__global__ __launch_bounds__(256) void k_prefix(P p) {
    const int idx = blockIdx.x * 256 + threadIdx.x;   // 0..131071
    bf16* q = p.SPD + (size_t)idx * 4;
    float run[4] = {0.f, 0.f, 0.f, 0.f};
    bf16x4 d[16];
#pragma unroll
    for (int cc = 0; cc < 16; ++cc)
        d[cc] = *(const bf16x4*)(q + (size_t)cc * 524288);
#pragma unroll
    for (int cc = 0; cc < 16; ++cc) {
        bf16x4 s;
#pragma unroll
        for (int e = 0; e < 4; ++e) s[e] = (bf16)run[e];
        *(bf16x4*)(q + (size_t)cc * 524288) = s;
#pragma unroll
        for (int e = 0; e < 4; ++e) run[e] += (float)d[cc][e];
    }
}

// ---------------------------------------------------------------------------
// k_out (r13 verbatim): block (c,bb,jh,oh), XCD-swizzled.
// ---------------------------------------------------------------------------
__global__ __launch_bounds__(512, 4) void k_out(P p) {
    const int bid = blockIdx.x;                  // 512
    const int xcd = bid & 7, idx = bid >> 3;     // idx 0..63
    const int c   = xcd + 8 * (idx >> 5);        // chunk 0..15
    const int rem = idx & 31;
    const int bb = rem >> 2, jh = (rem >> 1) & 1, oh = rem & 1;
    const int t = threadIdx.x, l = t & 63, w = t >> 6;
    const int lr = l & 15, lc = l >> 4;
    const int ot = oh * 8 + w;                   // o-tile 0..15
    const int hq = c * 2 + jh;                   // j half-chunk

    __shared__ __align__(16) bf16 PB[16][520];

    bf16x8 xa[8];
#pragma unroll
    for (int kk = 0; kk < 8; ++kk)
        xa[kk] = *(const bf16x8*)(p.XO + ((size_t)((hq * 8 + bb) * 8 + kk) * 64 + l) * 8);

    // ---- S^T phase over key halves hh = 0..jh ----
#pragma unroll
    for (int hh = 0; hh < 2; ++hh) {
        if (hh > jh) break;
        const int hk = c * 2 + hh;
        f32x4 sA = (f32x4){0.f, 0.f, 0.f, 0.f};
        f32x4 sS = (f32x4){0.f, 0.f, 0.f, 0.f};
#pragma unroll
        for (int kk = 0; kk < 8; ++kk) {
            const size_t ko = ((size_t)((hk * 8 + w) * 8 + kk) * 64 + l) * 8;
            sA = MFMA16(*(const bf16x8*)(p.A2GF + ko), xa[kk], sA);
            sS = MFMA16(*(const bf16x8*)(p.S2GF + ko), xa[kk], sS);
        }
        const int tl = w * 2 + (lc >> 1);
        const float ga =  p.sag[(c * 32 + hh * 16 + tl) * 8 + bb];
        const float gs = -p.ssg[(c * 32 + hh * 16 + tl) * 8 + bb];
        const bool m = (hh == jh) && (tl > lr);
        bf16x4 pa, ps;
#pragma unroll
        for (int v = 0; v < 4; ++v) {
            pa[v] = (bf16)(m ? 0.f : ga * sA[v]);
            ps[v] = (bf16)(m ? 0.f : gs * sS[v]);
        }
        *(bf16x4*)&PB[lr][hh * 128 + w * 16 + lc * 4]       = pa;
        *(bf16x4*)&PB[lr][256 + hh * 128 + w * 16 + lc * 4] = ps;
    }

    // ---- inter (state c) + base (W0) while PB settles ----
    f32x4 acco = (f32x4){0.f, 0.f, 0.f, 0.f};
#pragma unroll
    for (int kk = 0; kk < 8; ++kk) {
        const bf16x8 b = *(const bf16x8*)(p.SPD +
            ((size_t)(((c * 8 + bb) * 8 + kk) * 16 + ot) * 64 + l) * 8);
        acco = MFMA16(xa[kk], b, acco);
    }
#pragma unroll
    for (int kk = 0; kk < 8; ++kk) {
        const bf16x8 b = *(const bf16x8*)(p.WB +
            (((size_t)(64 + ot) * 8 + kk) * 64 + l) * 8);
        acco = MFMA16(xa[kk], b, acco);
    }

    __syncthreads();   // PB visible

    // ---- intra out phase over key halves ----
#pragma unroll
    for (int hh = 0; hh < 2; ++hh) {
        if (hh > jh) break;
        const int hk = c * 2 + hh;
#pragma unroll
        for (int kk2 = 0; kk2 < 4; ++kk2) {
            const bf16x8 af = *(const bf16x8*)&PB[lr][hh * 128 + kk2 * 32 + lc * 8];
            const bf16x8 b = *(const bf16x8*)(p.A1F +
                ((size_t)((hk * 4 + kk2) * 16 + ot) * 64 + l) * 8);
            acco = MFMA16(af, b, acco);
        }
#pragma unroll
        for (int kk2 = 0; kk2 < 4; ++kk2) {
            const bf16x8 af = *(const bf16x8*)&PB[lr][256 + hh * 128 + kk2 * 32 + lc * 8];
            const bf16x8 b = *(const bf16x8*)(p.S1F +
                ((size_t)((hk * 4 + kk2) * 16 + ot) * 64 + l) * 8);
            acco = MFMA16(af, b, acco);
        }
    }

    // ---- pure write ----
#pragma unroll
    for (int v = 0; v < 4; ++v) {
        const size_t jb = (size_t)((hq * 16 + lc * 4 + v) * 8 + bb);
        p.out[jb * 256 + ot * 16 + lr] = acco[v];
    }
}

// ---------------------------------------------------------------------------
extern "C" void kernel_launch(void* const* d_in, const int* in_sizes, int n_in,
                              void* d_out, int out_size, void* d_ws, size_t ws_size,
                              hipStream_t stream) {
    char* ws = (char*)d_ws;
    P hp;
    hp.x  = (const float*)d_in[0];
    hp.sw = (const float*)d_in[1];
    hp.sb = (const float*)d_in[2];
    hp.w0 = (const float*)d_in[3];
    hp.out = (float*)d_out;
    hp.WB   = (bf16*)(ws + 0);
    hp.XF   = (bf16*)(ws + 688128);
    hp.XO   = (bf16*)(ws + 2785280);
    hp.A1F  = (bf16*)(ws + 4882432);
    hp.S1F  = (bf16*)(ws + 6979584);
    hp.A2TF = (bf16*)(ws + 9076736);
    hp.S2TF = (bf16*)(ws + 11173888);
    hp.A2GF = (bf16*)(ws + 13271040);
    hp.S2GF = (bf16*)(ws + 15368192);
    hp.sag  = (float*)(ws + 17465344);     // 16 KB
    hp.ssg  = (float*)(ws + 17481728);     // 16 KB
    hp.SPD  = (bf16*)(ws + 17498112);      // 16 MB

    k_init<<<596, 256, 0, stream>>>(hp);
    dim3 gp(64, 17);
    k_prep<<<gp, 256, 0, stream>>>(hp);
    k_delta<<<256, 512, 0, stream>>>(hp);
    k_prefix<<<512, 256, 0, stream>>>(hp);
    k_out<<<512, 512, 0, stream>>>(hp);
}

// Round 17
// 55.370 us; speedup vs baseline: 1.3545x; 1.0323x over previous
//
#include <hip/hip_runtime.h>
#include <math.h>

typedef __bf16 bf16;
typedef __attribute__((ext_vector_type(4))) __bf16 bf16x4;
typedef __attribute__((ext_vector_type(8))) __bf16 bf16x8;
typedef __attribute__((ext_vector_type(4))) float f32x4;

#define MFMA16(a, b, c) __builtin_amdgcn_mfma_f32_16x16x32_bf16(a, b, c, 0, 0, 0)

struct P {
    const float* x; const float* sw; const float* sb; const float* w0;
    float* out;
    bf16 *WB, *XF, *XO, *A1F, *S1F, *A2TF, *S2TF, *A2GF, *S2GF, *SPD;
    float *sag, *ssg;
};

// ---------------------------------------------------------------------------
// k_init (r13 verbatim): bid<256 -> XF; bid<512 -> XO; else WB (84 tiles)
// ---------------------------------------------------------------------------
__global__ __launch_bounds__(256) void k_init(P p) {
    const int vb = blockIdx.x, vt = threadIdx.x;
    const int l = vt & 63, kb = vt >> 6;
    if (vb < 512) {
        const int col0 = (l >> 4) * 8;
#pragma unroll
        for (int pass = 0; pass < 2; ++pass) {
            const int kg = kb + pass * 4;
            size_t row;
            bf16* dst;
            if (vb < 256) {
                row = (size_t)(vb * 16 + (l & 15));
                dst = p.XF + ((size_t)(vb * 8 + kg) * 64 + l) * 8;
            } else {
                const int c = (vb - 256) >> 3, bb = (vb - 256) & 7;
                row = (size_t)((c * 16 + (l & 15)) * 8 + bb);
                dst = p.XO + ((size_t)(((c * 8 + bb) * 8) + kg) * 64 + l) * 8;
            }
            const float4 v0 = *(const float4*)(p.x + row * 256 + kg * 32 + col0);
            const float4 v1 = *(const float4*)(p.x + row * 256 + kg * 32 + col0 + 4);
            bf16x8 o;
            o[0] = (bf16)v0.x; o[1] = (bf16)v0.y; o[2] = (bf16)v0.z; o[3] = (bf16)v0.w;
            o[4] = (bf16)v1.x; o[5] = (bf16)v1.y; o[6] = (bf16)v1.z; o[7] = (bf16)v1.w;
            *(bf16x8*)dst = o;
        }
        return;
    }
    const int nb = vb - 512;                  // 0..83
    const int n = nb * 16 + (l & 15);
#pragma unroll
    for (int pass = 0; pass < 2; ++pass) {
        const int kk = kb + pass * 4;
        const int i0 = kk * 32 + (l >> 4) * 8;
        bf16x8 o;
        if (n < 1282) {
            const float* src = (n < 1024) ? (p.sw + (size_t)n * 256)
                             : (n < 1280) ? (p.w0 + (size_t)(n - 1024) * 256)
                                          : (p.sw + (size_t)(1024 + (n - 1280)) * 256);
#pragma unroll
            for (int e = 0; e < 8; ++e) o[e] = (bf16)src[i0 + e];
        } else {
#pragma unroll
            for (int e = 0; e < 8; ++e) o[e] = (bf16)0.0f;
        }
        *(bf16x8*)(p.WB + ((size_t)(nb * 8 + kk) * 64 + l) * 8) = o;
    }
}

// ---------------------------------------------------------------------------
// k_prep (r13 verbatim): grid (64, 17); y==16 -> gates (nb=20).
// ---------------------------------------------------------------------------
__global__ __launch_bounds__(256) void k_prep(P p) {
    const int mb = blockIdx.x;
    const int nb = (blockIdx.y == 16) ? 20 : blockIdx.y;
    const int vt = threadIdx.x;
    const int l = vt & 63, w = vt >> 6;
    const int lr = l & 15, lc = l >> 4;
    const int rw = mb * 64 + w * 16;
    const int n0 = nb * 64;

    f32x4 acc[4];
#pragma unroll
    for (int ni = 0; ni < 4; ++ni) acc[ni] = (f32x4){0.f, 0.f, 0.f, 0.f};

#pragma unroll
    for (int kk = 0; kk < 8; ++kk) {
        const bf16x8 a = *(const bf16x8*)(p.XF + ((size_t)((mb * 4 + w) * 8 + kk) * 64 + l) * 8);
#pragma unroll
        for (int ni = 0; ni < 4; ++ni) {
            const bf16x8 b = *(const bf16x8*)(p.WB +
                ((size_t)((nb * 4 + ni) * 8 + kk) * 64 + l) * 8);
            acc[ni] = MFMA16(a, b, acc[ni]);
        }
    }

    if (nb == 20) {   // gates
        if (lr < 2) {
            const float bz = p.sb[1024 + lr];
            float* dst = lr ? p.ssg : p.sag;
#pragma unroll
            for (int v2 = 0; v2 < 4; ++v2) {
                const float z = acc[0][v2] + bz;
                dst[rw + lc * 4 + v2] = 1.0f / (1.0f + expf(-z));
            }
        }
        return;
    }

    const int typ = nb >> 2;
    const int c   = mb >> 1;                  // half-chunk 0..31
    const int kkd = ((mb & 1) << 1) | (w >> 1);
    const int lcD = ((w & 1) << 1) | (lc >> 1);
    const int laneD = lr + 16 * lcD;
    const int eoff  = (lc & 1) * 4;

    if (typ == 0 || typ == 2) {   // A1F / S1F
        bf16* dst = (typ == 0 ? p.A1F : p.S1F);
        const int tb = (typ == 0 ? nb : nb - 8) * 4;
#pragma unroll
        for (int ni = 0; ni < 4; ++ni) {
            const float bz = p.sb[n0 + ni * 16 + lr];
            bf16x4 q;
#pragma unroll
            for (int v2 = 0; v2 < 4; ++v2) q[v2] = (bf16)(acc[ni][v2] + bz);
            *(bf16x4*)(dst + ((size_t)((c * 4 + kkd) * 16 + tb + ni) * 64 + laneD) * 8 + eoff) = q;
        }
    } else {                      // A2TF/S2TF + A2GF/S2GF
        bf16* dstT = (typ == 1 ? p.A2TF : p.S2TF);
        bf16* dstG = (typ == 1 ? p.A2GF : p.S2GF);
        const int nbr = (typ == 1 ? nb - 4 : nb - 12);
        const int keytile = mb * 4 + w;
#pragma unroll
        for (int ni = 0; ni < 4; ++ni) {
            const float bz = p.sb[n0 + ni * 16 + lr];
            bf16x4 q;
#pragma unroll
            for (int v2 = 0; v2 < 4; ++v2) q[v2] = (bf16)(acc[ni][v2] + bz);
            *(bf16x4*)(dstT + ((size_t)((c * 4 + kkd) * 16 + nbr * 4 + ni) * 64 + laneD) * 8 + eoff) = q;
            const int kkg = nbr * 2 + (ni >> 1);
            const int lcG = ((ni & 1) << 1) | (lr >> 3);
            const int eG  = lr & 7;
#pragma unroll
            for (int v2 = 0; v2 < 4; ++v2)
                dstG[((size_t)(keytile * 8 + kkg) * 64 + (lc * 4 + v2) + 16 * lcG) * 8 + eG] = q[v2];
        }
    }
}

// ---------------------------------------------------------------------------
// k_delta (r13 verbatim): per (c,bb,ih): delta[256 o][128 i-half], K=512.
// ---------------------------------------------------------------------------
#define KD_LDA(K) {                                                          \
    const bf16* As_ = ((K) < 8) ? p.A2TF : p.S2TF;                           \
    const int h_ = 2 * c + (((K) >> 2) & 1);                                 \
    _Pragma("unroll")                                                        \
    for (int mi = 0; mi < 4; ++mi)                                           \
        aC[mi] = *(const bf16x8*)(As_ +                                      \
            ((size_t)((h_ * 4 + ((K) & 3)) * 16 + itile0 + mi) * 64 + l) * 8); }

#define KD_LDB(K, bv) {                                                      \
    const bf16* Bs_ = ((K) < 8) ? p.A1F : p.S1F;                             \
    const int h_ = 2 * c + (((K) >> 2) & 1);                                 \
    _Pragma("unroll")                                                        \
    for (int ni = 0; ni < 4; ++ni)                                           \
        bv[ni] = *(const bf16x8*)(Bs_ +                                      \
            ((size_t)((h_ * 4 + ((K) & 3)) * 16 + otile0 + ni) * 64 + l) * 8); }

#define KD_SC(K, bv) {                                                       \
    const float* gp_ = ((K) < 8) ? p.sag : p.ssg;                            \
    float g_ = gp_[(c * 32 + ((K) & 7) * 4 + lc) * 8 + bb];                  \
    if ((K) >= 8) g_ = -g_;                                                  \
    _Pragma("unroll")                                                        \
    for (int ni = 0; ni < 4; ++ni)                                           \
        _Pragma("unroll")                                                    \
        for (int e = 0; e < 8; ++e)                                          \
            bv[ni][e] = (bf16)(g_ * (float)bv[ni][e]); }

#define KD_MM(bv) {                                                          \
    _Pragma("unroll")                                                        \
    for (int ni = 0; ni < 4; ++ni)                                           \
        _Pragma("unroll")                                                    \
        for (int mi = 0; mi < 4; ++mi)                                       \
            acc[mi][ni] = MFMA16(aC[mi], bv[ni], acc[mi][ni]); }

__global__ __launch_bounds__(512, 2) void k_delta(P p) {
    const int bid = blockIdx.x;                  // 256
    const int xcd = bid & 7, idx = bid >> 3;     // idx 0..31
    const int c   = xcd + 8 * (idx >> 4);        // chunk 0..15 (XCD-local)
    const int rem = idx & 15;
    const int bb  = rem >> 1, ih = rem & 1;
    const int t = threadIdx.x, l = t & 63, w = t >> 6;
    const int lc = l >> 4;
    const int itile0 = ih * 8 + (w >> 2) * 4;
    const int otile0 = (w & 3) * 4;

    f32x4 acc[4][4];
#pragma unroll
    for (int mi = 0; mi < 4; ++mi)
#pragma unroll
        for (int ni = 0; ni < 4; ++ni) acc[mi][ni] = (f32x4){0.f, 0.f, 0.f, 0.f};

    bf16x8 aC[4], bX[4], bY[4];

    KD_LDB(0, bX); KD_SC(0, bX);
    KD_LDA(0);  KD_LDB(1, bY);  KD_MM(bX); KD_SC(1, bY);
    KD_LDA(1);  KD_LDB(2, bX);  KD_MM(bY); KD_SC(2, bX);
    KD_LDA(2);  KD_LDB(3, bY);  KD_MM(bX); KD_SC(3, bY);
    KD_LDA(3);  KD_LDB(4, bX);  KD_MM(bY); KD_SC(4, bX);
    KD_LDA(4);  KD_LDB(5, bY);  KD_MM(bX); KD_SC(5, bY);
    KD_LDA(5);  KD_LDB(6, bX);  KD_MM(bY); KD_SC(6, bX);
    KD_LDA(6);  KD_LDB(7, bY);  KD_MM(bX); KD_SC(7, bY);
    KD_LDA(7);  KD_LDB(8, bX);  KD_MM(bY); KD_SC(8, bX);
    KD_LDA(8);  KD_LDB(9, bY);  KD_MM(bX); KD_SC(9, bY);
    KD_LDA(9);  KD_LDB(10, bX); KD_MM(bY); KD_SC(10, bX);
    KD_LDA(10); KD_LDB(11, bY); KD_MM(bX); KD_SC(11, bY);
    KD_LDA(11); KD_LDB(12, bX); KD_MM(bY); KD_SC(12, bX);
    KD_LDA(12); KD_LDB(13, bY); KD_MM(bX); KD_SC(13, bY);
    KD_LDA(13); KD_LDB(14, bX); KD_MM(bY); KD_SC(14, bX);
    KD_LDA(14); KD_LDB(15, bY); KD_MM(bX); KD_SC(15, bY);
    KD_LDA(15); KD_MM(bY);

    const size_t base = (size_t)(c * 8 + bb) * 8;
#pragma unroll
    for (int mi = 0; mi < 4; ++mi) {
        const int kkD  = ih * 4 + (w >> 2) * 2 + (mi >> 1);
        const int slot = (l & 15) + 16 * (((mi & 1) << 1) | (lc >> 1));
        const int eoff = (lc & 1) * 4;
#pragma unroll
        for (int ni = 0; ni < 4; ++ni) {
            bf16x4 q;
#pragma unroll
            for (int v = 0; v < 4; ++v) q[v] = (bf16)(acc[mi][ni][v]);
            *(bf16x4*)(p.SPD + ((base + kkD) * 16 + otile0 + ni) * 512 + slot * 8 + eoff) = q;
        }
    }
}

// ---------------------------------------------------------------------------
// k_prefix (r16 verbatim): in-place exclusive prefix, 16-deep load batch.
// ---------------------------------------------------------------------------
__global__ __launch_bounds__(256) void k_prefix(P p) {
    const int idx = blockIdx.x * 256 + threadIdx.x;   // 0..131071
    bf16* q = p.SPD + (size_t)idx * 4;
    float run[4] = {0.f, 0.f, 0.f, 0.f};
    bf16x4 d[16];
#pragma unroll
    for (int cc = 0; cc < 16; ++cc)
        d[cc] = *(const bf16x4*)(q + (size_t)cc * 524288);
#pragma unroll
    for (int cc = 0; cc < 16; ++cc) {
        bf16x4 s;
#pragma unroll
        for (int e = 0; e < 4; ++e) s[e] = (bf16)run[e];
        *(bf16x4*)(q + (size_t)cc * 524288) = s;
#pragma unroll
        for (int e = 0; e < 4; ++e) run[e] += (float)d[cc][e];
    }
}

// ---------------------------------------------------------------------------
// k_out (oh-merged): block (c,bb,jh), 256 blocks, 8 waves. Wave w computes
// S^T key tile w ONCE, then inter+base+intra for TWO o-tiles (w, w+8) with
// shared PB fragment loads. Arithmetic identical to r16; dedups S^T work
// and halves XO/A2GF/S2GF fetches.
// ---------------------------------------------------------------------------
__global__ __launch_bounds__(512, 2) void k_out(P p) {
    const int bid = blockIdx.x;                  // 256
    const int xcd = bid & 7, idx = bid >> 3;     // idx 0..31
    const int c   = xcd + 8 * (idx >> 4);        // chunk 0..15
    const int rem = idx & 15;
    const int bb = rem >> 1, jh = rem & 1;
    const int t = threadIdx.x, l = t & 63, w = t >> 6;
    const int lr = l & 15, lc = l >> 4;
    const int hq = c * 2 + jh;                   // j half-chunk

    __shared__ __align__(16) bf16 PB[16][520];

    bf16x8 xa[8];
#pragma unroll
    for (int kk = 0; kk < 8; ++kk)
        xa[kk] = *(const bf16x8*)(p.XO + ((size_t)((hq * 8 + bb) * 8 + kk) * 64 + l) * 8);

    // ---- S^T phase over key halves hh = 0..jh (computed ONCE per block) ----
#pragma unroll
    for (int hh = 0; hh < 2; ++hh) {
        if (hh > jh) break;
        const int hk = c * 2 + hh;
        f32x4 sA = (f32x4){0.f, 0.f, 0.f, 0.f};
        f32x4 sS = (f32x4){0.f, 0.f, 0.f, 0.f};
#pragma unroll
        for (int kk = 0; kk < 8; ++kk) {
            const size_t ko = ((size_t)((hk * 8 + w) * 8 + kk) * 64 + l) * 8;
            sA = MFMA16(*(const bf16x8*)(p.A2GF + ko), xa[kk], sA);
            sS = MFMA16(*(const bf16x8*)(p.S2GF + ko), xa[kk], sS);
        }
        const int tl = w * 2 + (lc >> 1);
        const float ga =  p.sag[(c * 32 + hh * 16 + tl) * 8 + bb];
        const float gs = -p.ssg[(c * 32 + hh * 16 + tl) * 8 + bb];
        const bool m = (hh == jh) && (tl > lr);
        bf16x4 pa, ps;
#pragma unroll
        for (int v = 0; v < 4; ++v) {
            pa[v] = (bf16)(m ? 0.f : ga * sA[v]);
            ps[v] = (bf16)(m ? 0.f : gs * sS[v]);
        }
        *(bf16x4*)&PB[lr][hh * 128 + w * 16 + lc * 4]       = pa;
        *(bf16x4*)&PB[lr][256 + hh * 128 + w * 16 + lc * 4] = ps;
    }

    // ---- inter (state c) + base (W0), both o-tiles, while PB settles ----
    f32x4 acc0 = (f32x4){0.f, 0.f, 0.f, 0.f};
    f32x4 acc1 = (f32x4){0.f, 0.f, 0.f, 0.f};
#pragma unroll
    for (int kk = 0; kk < 8; ++kk) {
        const bf16x8 b0 = *(const bf16x8*)(p.SPD +
            ((size_t)(((c * 8 + bb) * 8 + kk) * 16 + w) * 64 + l) * 8);
        const bf16x8 b1 = *(const bf16x8*)(p.SPD +
            ((size_t)(((c * 8 + bb) * 8 + kk) * 16 + 8 + w) * 64 + l) * 8);
        acc0 = MFMA16(xa[kk], b0, acc0);
        acc1 = MFMA16(xa[kk], b1, acc1);
    }
#pragma unroll
    for (int kk = 0; kk < 8; ++kk) {
        const bf16x8 b0 = *(const bf16x8*)(p.WB +
            (((size_t)(64 + w) * 8 + kk) * 64 + l) * 8);
        const bf16x8 b1 = *(const bf16x8*)(p.WB +
            (((size_t)(64 + 8 + w) * 8 + kk) * 64 + l) * 8);
        acc0 = MFMA16(xa[kk], b0, acc0);
        acc1 = MFMA16(xa[kk], b1, acc1);
    }

    __syncthreads();   // PB visible

    // ---- intra out phase over key halves, both o-tiles, shared af ----
#pragma unroll
    for (int hh = 0; hh < 2; ++hh) {
        if (hh > jh) break;
        const int hk = c * 2 + hh;
#pragma unroll
        for (int kk2 = 0; kk2 < 4; ++kk2) {
            const bf16x8 af = *(const bf16x8*)&PB[lr][hh * 128 + kk2 * 32 + lc * 8];
            const bf16x8 b0 = *(const bf16x8*)(p.A1F +
                ((size_t)((hk * 4 + kk2) * 16 + w) * 64 + l) * 8);
            const bf16x8 b1 = *(const bf16x8*)(p.A1F +
                ((size_t)((hk * 4 + kk2) * 16 + 8 + w) * 64 + l) * 8);
            acc0 = MFMA16(af, b0, acc0);
            acc1 = MFMA16(af, b1, acc1);
        }
#pragma unroll
        for (int kk2 = 0; kk2 < 4; ++kk2) {
            const bf16x8 af = *(const bf16x8*)&PB[lr][256 + hh * 128 + kk2 * 32 + lc * 8];
            const bf16x8 b0 = *(const bf16x8*)(p.S1F +
                ((size_t)((hk * 4 + kk2) * 16 + w) * 64 + l) * 8);
            const bf16x8 b1 = *(const bf16x8*)(p.S1F +
                ((size_t)((hk * 4 + kk2) * 16 + 8 + w) * 64 + l) * 8);
            acc0 = MFMA16(af, b0, acc0);
            acc1 = MFMA16(af, b1, acc1);
        }
    }

    // ---- pure writes (both o-tiles) ----
#pragma unroll
    for (int v = 0; v < 4; ++v) {
        const size_t jb = (size_t)((hq * 16 + lc * 4 + v) * 8 + bb);
        p.out[jb * 256 + w * 16 + lr]       = acc0[v];
        p.out[jb * 256 + (8 + w) * 16 + lr] = acc1[v];
    }
}

// ---------------------------------------------------------------------------
extern "C" void kernel_launch(void* const* d_in, const int* in_sizes, int n_in,
                              void* d_out, int out_size, void* d_ws, size_t ws_size,
                              hipStream_t stream) {
    char* ws = (char*)d_ws;
    P hp;
    hp.x  = (const float*)d_in[0];
    hp.sw = (const float*)d_in[1];
    hp.sb = (const float*)d_in[2];
    hp.w0 = (const float*)d_in[3];
    hp.out = (float*)d_out;
    hp.WB   = (bf16*)(ws + 0);
    hp.XF   = (bf16*)(ws + 688128);
    hp.XO   = (bf16*)(ws + 2785280);
    hp.A1F  = (bf16*)(ws + 4882432);
    hp.S1F  = (bf16*)(ws + 6979584);
    hp.A2TF = (bf16*)(ws + 9076736);
    hp.S2TF = (bf16*)(ws + 11173888);
    hp.A2GF = (bf16*)(ws + 13271040);
    hp.S2GF = (bf16*)(ws + 15368192);
    hp.sag  = (float*)(ws + 17465344);     // 16 KB
    hp.ssg  = (float*)(ws + 17481728);     // 16 KB
    hp.SPD  = (bf16*)(ws + 17498112);      // 16 MB

    k_init<<<596, 256, 0, stream>>>(hp);
    dim3 gp(64, 17);
    k_prep<<<gp, 256, 0, stream>>>(hp);
    k_delta<<<256, 512, 0, stream>>>(hp);
    k_prefix<<<512, 256, 0, stream>>>(hp);
    k_out<<<256, 512, 0, stream>>>(hp);
}